// Round 4
// baseline (250.325 us; speedup 1.0000x reference)
//
#include <hip/hip_runtime.h>

// LIF recurrence, T=4, TAU=1.0, THRESH=1.0.
// mem = mem + x[t]; spike = (mem - 1 > 0); mem = spike ? 0 : mem.
//
// R3 analysis: one-column-per-thread version pinned at 2.3 TB/s, VGPR=16,
// VALUBusy 3.5% -> latency-bound (too few bytes in flight per wave), NOT
// BW-bound (harness fill hits 6.6 TB/s). Fix: each thread owns 4 columns
// (stride = total thread count, so lanes stay coalesced) x 4 timesteps
// = 16 independent 16B loads in flight per thread before any dependent use.

#define LIF_T 4
#define COLS  4   // float4 columns per thread

typedef float v4f __attribute__((ext_vector_type(4)));

__global__ __launch_bounds__(256) void
lif_spike_kernel(const float* __restrict__ x, float* __restrict__ out, int n_vec, int n) {
    const int tid     = blockIdx.x * blockDim.x + threadIdx.x;
    const int nthread = gridDim.x * blockDim.x;   // == n_vec / COLS

    // Column c handled by this thread: tid + c*nthread  (coalesced per c).
    // Phase 1: 16 independent loads.
    v4f xt[COLS][LIF_T];
#pragma unroll
    for (int c = 0; c < COLS; ++c) {
        const size_t col = (size_t)(tid + c * nthread) * 4;
#pragma unroll
        for (int t = 0; t < LIF_T; ++t) {
            xt[c][t] = *reinterpret_cast<const v4f*>(x + (size_t)t * n + col);
        }
    }

    // Phase 2: recurrence per column, in registers.
    v4f sp[COLS][LIF_T];
#pragma unroll
    for (int c = 0; c < COLS; ++c) {
        v4f mem = (v4f)(0.0f);
#pragma unroll
        for (int t = 0; t < LIF_T; ++t) {
            mem += xt[c][t];
            v4f s;
            s.x = (mem.x > 1.0f) ? 1.0f : 0.0f;
            s.y = (mem.y > 1.0f) ? 1.0f : 0.0f;
            s.z = (mem.z > 1.0f) ? 1.0f : 0.0f;
            s.w = (mem.w > 1.0f) ? 1.0f : 0.0f;
            sp[c][t] = s;
            mem.x = (s.x > 0.f) ? 0.f : mem.x;
            mem.y = (s.y > 0.f) ? 0.f : mem.y;
            mem.z = (s.z > 0.f) ? 0.f : mem.z;
            mem.w = (s.w > 0.f) ? 0.f : mem.w;
        }
    }

    // Phase 3: 16 nontemporal stores (output is write-once).
#pragma unroll
    for (int c = 0; c < COLS; ++c) {
        const size_t col = (size_t)(tid + c * nthread) * 4;
#pragma unroll
        for (int t = 0; t < LIF_T; ++t) {
            __builtin_nontemporal_store(sp[c][t],
                reinterpret_cast<v4f*>(out + (size_t)t * n + col));
        }
    }
}

extern "C" void kernel_launch(void* const* d_in, const int* in_sizes, int n_in,
                              void* d_out, int out_size, void* d_ws, size_t ws_size,
                              hipStream_t stream) {
    const float* x = (const float*)d_in[0];
    float* out = (float*)d_out;

    int n = out_size / LIF_T;          // elements per timestep (8,388,608)
    int n_vec = n / 4;                 // float4 columns (2,097,152)

    int block = 256;
    int grid = n_vec / (block * COLS); // 2048 blocks (n_vec divisible: 2^21)
    lif_spike_kernel<<<grid, block, 0, stream>>>(x, out, n_vec, n);
}

// Round 5
// 239.918 us; speedup vs baseline: 1.0434x; 1.0434x over previous
//
#include <hip/hip_runtime.h>

// LIF recurrence, T=4, TAU=1.0, THRESH=1.0.
// mem = mem + x[t]; spike = (mem - 1 > 0); mem = spike ? 0 : mem.
//
// R5 structure: persistent grid-stride loop with explicit software pipeline.
// Prior one-shot thread-per-element variants (R0/R2/R4) all pinned at
// 2.0-2.3 TB/s: each wave lived exactly one memory round-trip, so offered
// load per CU was latency-capped regardless of occupancy. The 6.3 TB/s
// float4-copy idiom (m13) is a long-lived loop where iter k+1's loads are
// issued before iter k's data is consumed -> loads continuously in flight.
// We replicate that: prefetch next column's 4 timestep-loads, then
// compute+store the current column.

#define LIF_T 4

typedef float v4f __attribute__((ext_vector_type(4)));

__device__ __forceinline__ void lif_compute_store(const v4f xt[LIF_T],
                                                  float* __restrict__ out,
                                                  int n, size_t col) {
    v4f mem = (v4f)(0.0f);
#pragma unroll
    for (int t = 0; t < LIF_T; ++t) {
        mem += xt[t];
        v4f s;
        s.x = (mem.x > 1.0f) ? 1.0f : 0.0f;
        s.y = (mem.y > 1.0f) ? 1.0f : 0.0f;
        s.z = (mem.z > 1.0f) ? 1.0f : 0.0f;
        s.w = (mem.w > 1.0f) ? 1.0f : 0.0f;
        mem.x = (s.x > 0.f) ? 0.f : mem.x;
        mem.y = (s.y > 0.f) ? 0.f : mem.y;
        mem.z = (s.z > 0.f) ? 0.f : mem.z;
        mem.w = (s.w > 0.f) ? 0.f : mem.w;
        __builtin_nontemporal_store(s, reinterpret_cast<v4f*>(out + (size_t)t * n + col));
    }
}

__global__ __launch_bounds__(256, 8) void
lif_spike_kernel(const float* __restrict__ x, float* __restrict__ out, int n_vec, int n) {
    const int tid     = blockIdx.x * blockDim.x + threadIdx.x;
    const int nthread = gridDim.x * blockDim.x;

    int idx = tid;
    if (idx >= n_vec) return;

    // Pipeline prologue: load column idx (4 independent 16B loads).
    v4f cur[LIF_T];
#pragma unroll
    for (int t = 0; t < LIF_T; ++t) {
        cur[t] = *reinterpret_cast<const v4f*>(x + (size_t)t * n + (size_t)idx * 4);
    }

    // Steady state: issue next column's loads, then consume+store current.
    for (int nidx = idx + nthread; nidx < n_vec; nidx += nthread) {
        v4f nxt[LIF_T];
#pragma unroll
        for (int t = 0; t < LIF_T; ++t) {
            nxt[t] = *reinterpret_cast<const v4f*>(x + (size_t)t * n + (size_t)nidx * 4);
        }

        lif_compute_store(cur, out, n, (size_t)idx * 4);

#pragma unroll
        for (int t = 0; t < LIF_T; ++t) cur[t] = nxt[t];
        idx = nidx;
    }

    // Epilogue: last column.
    lif_compute_store(cur, out, n, (size_t)idx * 4);
}

extern "C" void kernel_launch(void* const* d_in, const int* in_sizes, int n_in,
                              void* d_out, int out_size, void* d_ws, size_t ws_size,
                              hipStream_t stream) {
    const float* x = (const float*)d_in[0];
    float* out = (float*)d_out;

    int n = out_size / LIF_T;          // elements per timestep (8,388,608)
    int n_vec = n / 4;                 // float4 columns (2,097,152)

    int block = 256;
    int grid  = 2048;                  // 8 blocks/CU on 256 CUs; 4 iters/thread
    lif_spike_kernel<<<grid, block, 0, stream>>>(x, out, n_vec, n);
}

// Round 6
// 231.123 us; speedup vs baseline: 1.0831x; 1.0381x over previous
//
#include <hip/hip_runtime.h>

// LIF recurrence, T=4, TAU=1.0, THRESH=1.0.
// mem = mem + x[t]; spike = (mem - 1 > 0); mem = spike ? 0 : mem.
//
// R6 theory: all prior variants pinned at ~3.2 TB/s combined regardless of
// scheduling structure -> memory system caps THIS PATTERN, not the wave
// pipeline (queueing equilibrium: loaded latency back-computes to ~5us).
// The 8 per-wave streams (4 ld + 4 st) sit exactly 32 MiB apart = same HBM
// channel bits, interleaving 1 KiB R/W bursts per channel. This round:
// each wave issues 4 CONSECUTIVE coalesced float4 instructions per t-plane
// (4 KiB contiguous per channel visit, lanes still contiguous per instr)
// to lengthen per-stream bursts and cut R/W turnaround frequency.

#define LIF_T 4
#define CHUNK 4   // consecutive wave-wide float4 instructions per t-plane

typedef float v4f __attribute__((ext_vector_type(4)));

__global__ __launch_bounds__(256) void
lif_spike_kernel(const float* __restrict__ x, float* __restrict__ out, int n) {
    const int lane = threadIdx.x & 63;
    const int wv   = (blockIdx.x * blockDim.x + threadIdx.x) >> 6;  // global wave id

    // Wave covers float4 columns [wv*256, wv*256+256) in each t-plane;
    // instruction c covers a contiguous 1 KiB right after instruction c-1.
    const size_t wbase = (size_t)wv * (64 * CHUNK);

    // Loads: 16 per thread; per t-plane a 4 KiB contiguous wave burst.
    v4f xt[LIF_T][CHUNK];
#pragma unroll
    for (int t = 0; t < LIF_T; ++t) {
        const float* px = x + (size_t)t * n;
#pragma unroll
        for (int c = 0; c < CHUNK; ++c) {
            size_t col = wbase + (size_t)c * 64 + lane;
            xt[t][c] = *reinterpret_cast<const v4f*>(px + col * 4);
        }
    }

    // Recurrence in registers.
    v4f sp[LIF_T][CHUNK];
#pragma unroll
    for (int c = 0; c < CHUNK; ++c) {
        v4f mem = (v4f)(0.0f);
#pragma unroll
        for (int t = 0; t < LIF_T; ++t) {
            mem += xt[t][c];
            v4f s;
            s.x = (mem.x > 1.0f) ? 1.0f : 0.0f;
            s.y = (mem.y > 1.0f) ? 1.0f : 0.0f;
            s.z = (mem.z > 1.0f) ? 1.0f : 0.0f;
            s.w = (mem.w > 1.0f) ? 1.0f : 0.0f;
            sp[t][c] = s;
            mem.x = (s.x > 0.f) ? 0.f : mem.x;
            mem.y = (s.y > 0.f) ? 0.f : mem.y;
            mem.z = (s.z > 0.f) ? 0.f : mem.z;
            mem.w = (s.w > 0.f) ? 0.f : mem.w;
        }
    }

    // Stores: per t-plane a 4 KiB contiguous wave burst (write-once -> NT).
#pragma unroll
    for (int t = 0; t < LIF_T; ++t) {
        float* po = out + (size_t)t * n;
#pragma unroll
        for (int c = 0; c < CHUNK; ++c) {
            size_t col = wbase + (size_t)c * 64 + lane;
            __builtin_nontemporal_store(sp[t][c], reinterpret_cast<v4f*>(po + col * 4));
        }
    }
}

extern "C" void kernel_launch(void* const* d_in, const int* in_sizes, int n_in,
                              void* d_out, int out_size, void* d_ws, size_t ws_size,
                              hipStream_t stream) {
    const float* x = (const float*)d_in[0];
    float* out = (float*)d_out;

    int n = out_size / LIF_T;          // elements per timestep (8,388,608)
    int n_vec = n / 4;                 // float4 columns (2,097,152)

    int block = 256;                   // 4 waves/block
    // Each wave handles 256 float4 columns -> each block 1024.
    int grid = n_vec / (block / 64 * 64 * CHUNK);   // 2048 blocks
    lif_spike_kernel<<<grid, block, 0, stream>>>(x, out, n);
}